// Round 7
// baseline (184.885 us; speedup 1.0000x reference)
//
#include <hip/hip_runtime.h>
#include <math.h>

// Problem constants (from reference setup_inputs)
#define BB 8
#define CC 192
#define HH 128
#define WW 128
#define TH 16                 // output rows per tile
#define NTILE 8               // tiles per image
#define SLOTS 18              // input rows per tile (halo included)
#define TILE_FLOATS (SLOTS * WW)   // 2304 floats = 9216 B per buffer

typedef float vf4 __attribute__((ext_vector_type(4)));

// Direct global->LDS DMA, 16 B per lane, no VGPR destination.
__device__ __forceinline__ void gl_lds16(const float* g, float* l) {
    __builtin_amdgcn_global_load_lds(
        (const __attribute__((address_space(1))) void*)g,
        (__attribute__((address_space(3))) void*)l,
        16, 0, 0);
}

__device__ __forceinline__ float col9(float a0, float a1, float a2,
                                      float b0, float b1, float b2,
                                      float c0, float c1, float c2,
                                      float th, const float* kk) {
    float m;
    m = fmaf(th, kk[0], a0);
    m = fmaxf(m, fmaf(th, kk[1], a1));
    m = fmaxf(m, fmaf(th, kk[2], a2));
    m = fmaxf(m, fmaf(th, kk[3], b0));
    m = fmaxf(m, fmaf(th, kk[4], b1));
    m = fmaxf(m, fmaf(th, kk[5], b2));
    m = fmaxf(m, fmaf(th, kk[6], c0));
    m = fmaxf(m, fmaf(th, kk[7], c1));
    m = fmaxf(m, fmaf(th, kk[8], c2));
    return m;
}

__global__ __launch_bounds__(256) void dynmorph_kernel(
    const float* __restrict__ x,      // [B, C, H, W]
    const float* __restrict__ kern,   // [C, 9]
    const float* __restrict__ gw,     // [C]
    const float* __restrict__ gb,     // [C]
    float* __restrict__ out)          // [B, C, H, W]
{
    __shared__ __attribute__((aligned(16))) float sbuf[2][TILE_FLOATS];

    const int tid  = threadIdx.x;
    const int lane = tid & 63;
    const int wv   = tid >> 6;       // wave 0..3
    const int wg   = lane & 31;      // column group (cols 4*wg..4*wg+3)
    const int half = lane >> 5;      // row parity within wave
    const int col  = wg * 4;

    const int bc = blockIdx.x;       // b*C + c (block-uniform)
    const int c  = bc % CC;

    const float* xp = x   + (size_t)bc * (HH * WW);
    float*       op = out + (size_t)bc * (HH * WW);

    // Block-uniform coefficients -> scalar regs
    float kk[9];
#pragma unroll
    for (int i = 0; i < 9; ++i) kk[i] = kern[c * 9 + i];
    const float gwc = gw[c];
    const float gbc = gb[c];

    // ---- Issue DMA loads for tile tt into sbuf[tt&1] ----
    // LDS slot s (512 B each) <-> input row (16*tt - 1 + s); load i covers
    // slots 2i,2i+1 (1024 B = one 64-lane global_load_lds).
    auto issue_tile = [&](int tt) {
        float* lb = &sbuf[tt & 1][0];
        const int base = tt * TH - 1;              // first input row (may be -1)
        for (int i = wv; i < 9; i += 4) {          // wave wv owns loads wv, wv+4, wv+8
            const int gr = base + 2 * i;           // row pair (gr, gr+1)
            const float* g = xp + gr * WW + lane * 4;
            float*       l = lb + i * 256;
            if (gr >= 0 && gr + 1 < HH) {
                gl_lds16(g, l);                    // full 2 rows
            } else if (gr < 0) {
                if (lane >= 32) gl_lds16(g, l);    // row 0 only (upper half lanes)
            } else if (gr < HH) {
                if (lane < 32) gl_lds16(g, l);     // row 127 only (lower half lanes)
            }
        }
        // Zero-padding halo rows
        if (tt == 0         && tid < WW) lb[tid] = 0.0f;            // slot 0 = row -1
        if (tt == NTILE - 1 && tid < WW) lb[17 * WW + tid] = 0.0f;  // slot 17 = row 128
    };

    // ---- Compute tile tt from sbuf[tt&1] ----
    auto compute_tile = [&](int tt) {
        const float* lb = &sbuf[tt & 1][0];
        const int r0 = tt * TH;
#pragma unroll
        for (int i = 0; i < 2; ++i) {
            const int rr = 4 * wv + 2 * i + half;  // local output row 0..15
            // input slots rr, rr+1, rr+2
            const vf4 A  = *(const vf4*)(lb + (rr    ) * WW + col);
            const vf4 B  = *(const vf4*)(lb + (rr + 1) * WW + col);
            const vf4 Cv = *(const vf4*)(lb + (rr + 2) * WW + col);

            // w-halo via intra-32-lane shuffles (wg 0/31 are image borders)
            float lA = __shfl_up(A.w, 1),  rA = __shfl_down(A.x, 1);
            float lB = __shfl_up(B.w, 1),  rB = __shfl_down(B.x, 1);
            float lC = __shfl_up(Cv.w, 1), rC = __shfl_down(Cv.x, 1);
            lA = (wg == 0)  ? 0.0f : lA;
            lB = (wg == 0)  ? 0.0f : lB;
            lC = (wg == 0)  ? 0.0f : lC;
            rA = (wg == 31) ? 0.0f : rA;
            rB = (wg == 31) ? 0.0f : rB;
            rC = (wg == 31) ? 0.0f : rC;

            const float t0 = __builtin_amdgcn_rcpf(1.0f + __expf(-fmaf(B.x, gwc, gbc)));
            const float t1 = __builtin_amdgcn_rcpf(1.0f + __expf(-fmaf(B.y, gwc, gbc)));
            const float t2 = __builtin_amdgcn_rcpf(1.0f + __expf(-fmaf(B.z, gwc, gbc)));
            const float t3 = __builtin_amdgcn_rcpf(1.0f + __expf(-fmaf(B.w, gwc, gbc)));

            vf4 o;
            o.x = col9(lA,  A.x, A.y,
                       lB,  B.x, B.y,
                       lC,  Cv.x, Cv.y, t0, kk);
            o.y = col9(A.x, A.y, A.z,
                       B.x, B.y, B.z,
                       Cv.x, Cv.y, Cv.z, t1, kk);
            o.z = col9(A.y, A.z, A.w,
                       B.y, B.z, B.w,
                       Cv.y, Cv.z, Cv.w, t2, kk);
            o.w = col9(A.z, A.w, rA,
                       B.z, B.w, rB,
                       Cv.z, Cv.w, rC,  t3, kk);

            __builtin_nontemporal_store(o, (vf4*)(op + (r0 + rr) * WW + col));
        }
    };

    // ---- Software pipeline: DMA(t+1) overlaps compute(t) ----
    issue_tile(0);
    __syncthreads();                // drains wave's own DMAs (vmcnt) + barrier
    for (int tt = 0; tt < NTILE; ++tt) {
        if (tt + 1 < NTILE) issue_tile(tt + 1);
        compute_tile(tt);
        __syncthreads();            // publishes sbuf[(tt+1)&1] for next iter
    }
}

extern "C" void kernel_launch(void* const* d_in, const int* in_sizes, int n_in,
                              void* d_out, int out_size, void* d_ws, size_t ws_size,
                              hipStream_t stream) {
    const float* x    = (const float*)d_in[0];
    const float* kern = (const float*)d_in[1];
    const float* gw   = (const float*)d_in[2];
    const float* gb   = (const float*)d_in[3];
    float* out        = (float*)d_out;

    dim3 grid(BB * CC);   // 1536 blocks = 6 per CU, one per (b, c) image
    dim3 block(256);
    dynmorph_kernel<<<grid, block, 0, stream>>>(x, kern, gw, gb, out);
}